// Round 3
// baseline (289.067 us; speedup 1.0000x reference)
//
#include <hip/hip_runtime.h>

#define TT 256
#define CC 256
#define LLAB 64
#define NEGF -1e30f
#define EPSF 1e-7f
#define DPTH 16           // prefetch depth; statically indexed ring (full unroll)

__device__ __forceinline__ float lse2f(float a, float b) {
    float m = fmaxf(a, b);
    return m + __logf(__expf(a - m) + __expf(b - m));
}
__device__ __forceinline__ float lse3f(float a, float b, float c) {
    float m = fmaxf(fmaxf(a, b), c);
    return m + __logf(__expf(a - m) + __expf(b - m) + __expf(c - m));
}

// One wave per batch item. Lane l owns extended states {2l, 2l+1}; lane 63
// additionally owns state 128 (blank) in s2. Per step: one shfl_up (the only
// cross-lane dep), lse math, and two scattered 4B loads (blank col + this
// lane's label col) prefetched DPTH=16 steps ahead through a statically
// indexed register ring (full unroll -> no rotation copies -> compiler emits
// counted s_waitcnt vmcnt(N), ~1400 cy of latency cover). Logs computed at
// consumption, off the serial alpha chain.
extern "C" __global__ __launch_bounds__(64) void ctc_fwd(
    const float* __restrict__ y_pred,
    const int* __restrict__ labels,
    const int* __restrict__ input_length,
    const int* __restrict__ label_length,
    float* __restrict__ out)
{
    const int b = blockIdx.x;
    const int l = threadIdx.x;

    const int lab  = labels[b * LLAB + l];
    const int labp = __shfl_up(lab, 1);
    const bool skip_ok = (l >= 1) && (lab != labp);

    int len = input_length[b];
    len = len < 1 ? 1 : (len > TT ? TT : len);
    const int tmax = len - 1;

    const float* __restrict__ yp = y_pred + (size_t)b * (TT * CC);
    const float* __restrict__ pb = yp + (CC - 1);  // blank column (uniform addr)
    const float* __restrict__ pl = yp + lab;       // this lane's label column

    // t = 0 init
    float s0 = (l == 0) ? __logf(pb[0] + EPSF) : NEGF;  // alpha[2l]
    float s1 = (l == 0) ? __logf(pl[0] + EPSF) : NEGF;  // alpha[2l+1]
    float s2 = NEGF;                                    // alpha[128] (lane 63)

    // preload ring for t = 1..DPTH (clamped to tmax)
    float rb[DPTH], rl[DPTH];
#pragma unroll
    for (int j = 0; j < DPTH; ++j) {
        int tt = 1 + j; tt = tt > tmax ? tmax : tt;
        const int o = tt * CC;
        rb[j] = pb[o];
        rl[j] = pl[o];
    }

    for (int tb = 1; tb < len; tb += DPTH) {
#pragma unroll
        for (int j = 0; j < DPTH; ++j) {
            const int t = tb + j;
            // consume slot j, then refill it for t + DPTH
            float eb = __logf(rb[j] + EPSF);
            float el = __logf(rl[j] + EPSF);
            int tp = t + DPTH; tp = tp > tmax ? tmax : tp;
            const int o = tp * CC;
            rb[j] = pb[o];
            rl[j] = pl[o];

            float am1 = __shfl_up(s1, 1);
            if (l == 0) am1 = NEGF;
            float n0 = lse2f(s0, am1) + eb;                        // state 2l
            float n1 = lse3f(s1, s0, skip_ok ? am1 : NEGF) + el;   // state 2l+1
            float n2 = lse2f(s2, s1) + eb;                         // state 128
            const bool act = t < len;
            s0 = act ? n0 : s0;
            s1 = act ? n1 : s1;
            s2 = act ? n2 : s2;
        }
    }

    int ll = label_length[b];
    ll = ll < 1 ? 1 : (ll > LLAB ? LLAB : ll);
    float v1 = __shfl(s1, ll - 1);                               // state 2*ll-1
    float v2 = (ll < LLAB) ? __shfl(s0, ll) : __shfl(s2, 63);    // state 2*ll
    if (l == 0) out[b] = -lse2f(v1, v2);
}

extern "C" void kernel_launch(void* const* d_in, const int* in_sizes, int n_in,
                              void* d_out, int out_size, void* d_ws, size_t ws_size,
                              hipStream_t stream) {
    const float* y_pred       = (const float*)d_in[0];
    const int*   labels       = (const int*)d_in[1];
    const int*   input_length = (const int*)d_in[2];
    const int*   label_length = (const int*)d_in[3];
    float* out = (float*)d_out;

    const int B = in_sizes[2];
    ctc_fwd<<<dim3(B), dim3(64), 0, stream>>>(y_pred, labels, input_length, label_length, out);
}

// Round 5
// 207.268 us; speedup vs baseline: 1.3946x; 1.3946x over previous
//
#include <hip/hip_runtime.h>

#define TT 256
#define CC 256
#define LLAB 64
#define NEGF -1e30f
#define EPSF 1e-7f
#define CH 16            // timesteps per chunk
#define NSLOT 4          // LDS ring slots

__device__ __forceinline__ float lse2f(float a, float b) {
    float m = fmaxf(a, b);
    return m + __logf(__expf(a - m) + __expf(b - m));
}
__device__ __forceinline__ float lse3f(float a, float b, float c) {
    float m = fmaxf(fmaxf(a, b), c);
    return m + __logf(__expf(a - m) + __expf(b - m) + __expf(c - m));
}

// am1[l] = x[l-1]; lane 0 -> NEGF (from the `old` operand, bound_ctrl=false).
// DPP WAVE_SHR1 (0x138): ~2cy VALU vs ~50cy ds_bpermute for __shfl_up.
__device__ __forceinline__ float wave_shr1(float x) {
    int r = __builtin_amdgcn_update_dpp(__float_as_int(NEGF), __float_as_int(x),
                                        0x138, 0xF, 0xF, false);
    return __int_as_float(r);
}

// One block (128 thr = 2 waves) per batch item.
// Wave 1 (producer): no serial dependency. 2-deep pipelined gather of emit
//   probs (scattered label cols + blank col), __logf off-chain, ds_write into
//   a 4-slot LDS ring. Loads for chunk c are issued one full window before
//   they are consumed by the producer itself (counted vmcnt by construction).
// Wave 0 (consumer): per window, pull 16 pre-logged emit pairs LDS->regs,
//   then run the alpha recurrence entirely in registers. Cross-lane dep is
//   one DPP wave_shr:1 per step. Barrier per window.
extern "C" __global__ __launch_bounds__(128) void ctc_fwd(
    const float* __restrict__ y_pred,
    const int* __restrict__ labels,
    const int* __restrict__ input_length,
    const int* __restrict__ label_length,
    float* __restrict__ out)
{
    const int b   = blockIdx.x;
    const int l   = threadIdx.x & 63;
    const int wid = threadIdx.x >> 6;

    __shared__ float lab_lds[NSLOT][CH][LLAB];
    __shared__ float blank_lds[NSLOT][CH];

    int len = input_length[b];
    len = len < 1 ? 1 : (len > TT ? TT : len);
    const int tmax = len - 1;
    const int nch  = (len - 1 + CH - 1) / CH;   // chunks of the t=1..len-1 recurrence

    const int lab = labels[b * LLAB + l];
    const float* __restrict__ yp = y_pred + (size_t)b * (TT * CC);
    const float* __restrict__ pl = yp + lab;       // this lane's label column
    const float* __restrict__ pb = yp + (CC - 1);  // blank column

    // ---- consumer state (wave 0) ----
    float s0 = NEGF, s1 = NEGF, s2 = NEGF;
    bool skip_ok = false;

    // ---- producer register sets (wave 1) ----
    float labA[CH], labB[CH], blA = 0.f, blB = 0.f;

#define ISSUE(c, labv, blv)                                                  \
    {                                                                        \
        const int t0 = 1 + (c) * CH;                                         \
        _Pragma("unroll")                                                    \
        for (int j = 0; j < CH; ++j) {                                       \
            int t = t0 + j; t = t > tmax ? tmax : t;                         \
            labv[j] = pl[t * CC];                                            \
        }                                                                    \
        { int t = t0 + (l & 15); t = t > tmax ? tmax : t;                    \
          blv = pb[t * CC]; }                                                \
    }

#define FINISH(c, labv, blv)                                                 \
    {                                                                        \
        const int slot_ = (c) % NSLOT;                                       \
        float lg_ = __logf((blv) + EPSF);                                    \
        if (l < CH) blank_lds[slot_][l] = lg_;                               \
        _Pragma("unroll")                                                    \
        for (int j = 0; j < CH; ++j)                                         \
            lab_lds[slot_][j][l] = __logf(labv[j] + EPSF);                   \
    }

    if (wid == 1) {
        // prologue: chunk0 -> B, chunk1 -> A; write chunk0
        ISSUE(0, labB, blB);
        ISSUE(1, labA, blA);
        FINISH(0, labB, blB);
    } else {
        const int labp = __shfl_up(lab, 1);
        skip_ok = (l >= 1) && (lab != labp);
        // t = 0 init (overlaps with producer prologue)
        if (l == 0) {
            s0 = __logf(pb[0] + EPSF);
            s1 = __logf(pl[0] + EPSF);
        }
    }
    __syncthreads();

    for (int k = 0; k < nch; ++k) {
        if (wid == 1) {
            // issue chunk k+2, finish chunk k+1 (its loads are one window old).
            // Writes go to slot (k+1)%4, consumer reads slot k%4 — disjoint.
            if ((k & 1) == 0) { ISSUE(k + 2, labB, blB); FINISH(k + 1, labA, blA); }
            else              { ISSUE(k + 2, labA, blA); FINISH(k + 1, labB, blB); }
        } else {
            const int slot = k % NSLOT;
            float e[CH], bb[CH];
#pragma unroll
            for (int j = 0; j < CH; ++j) {
                e[j]  = lab_lds[slot][j][l];
                bb[j] = blank_lds[slot][j];
            }
#pragma unroll
            for (int j = 0; j < CH; ++j) {
                const int t = 1 + k * CH + j;
                float am1 = wave_shr1(s1);
                float n0 = lse2f(s0, am1) + bb[j];                       // state 2l
                float n1 = lse3f(s1, s0, skip_ok ? am1 : NEGF) + e[j];   // state 2l+1
                float n2 = lse2f(s2, s1) + bb[j];                        // state 128
                const bool act = t < len;
                s0 = act ? n0 : s0;
                s1 = act ? n1 : s1;
                s2 = act ? n2 : s2;
            }
        }
        __syncthreads();
    }

    if (wid == 0) {
        int ll = label_length[b];
        ll = ll < 1 ? 1 : (ll > LLAB ? LLAB : ll);
        float v1 = __shfl(s1, ll - 1);                              // state 2*ll-1
        float v2 = (ll < LLAB) ? __shfl(s0, ll) : __shfl(s2, 63);   // state 2*ll
        if (l == 0) out[b] = -lse2f(v1, v2);
    }
}

extern "C" void kernel_launch(void* const* d_in, const int* in_sizes, int n_in,
                              void* d_out, int out_size, void* d_ws, size_t ws_size,
                              hipStream_t stream) {
    (void)n_in; (void)out_size; (void)d_ws; (void)ws_size;
    const float* y_pred       = (const float*)d_in[0];
    const int*   labels       = (const int*)d_in[1];
    const int*   input_length = (const int*)d_in[2];
    const int*   label_length = (const int*)d_in[3];
    float* out = (float*)d_out;

    const int B = in_sizes[2];
    ctc_fwd<<<dim3(B), dim3(128), 0, stream>>>(y_pred, labels, input_length, label_length, out);
}

// Round 6
// 192.606 us; speedup vs baseline: 1.5008x; 1.0761x over previous
//
#include <hip/hip_runtime.h>

#define TT 256
#define CC 256
#define LLAB 64
#define EPSF 1e-7f
#define CH 32            // timesteps per chunk
#define NSLOT 2          // LDS ring slots
#define LN2F 0.69314718055994531f

// am1[l] = x[l-1]; lane 0 -> 0.0f (prob-domain identity) via `old` operand.
__device__ __forceinline__ float wave_shr1_zero(float x) {
    int r = __builtin_amdgcn_update_dpp(0, __float_as_int(x), 0x138, 0xF, 0xF, false);
    return __int_as_float(r);
}

// Full 64-lane max (values >= 0), returned wave-uniform via readlane(63).
// row_shr 1/2/4/8 then row_bcast15/31; old = x keeps invalid lanes harmless.
__device__ __forceinline__ float wave_max64(float x) {
#define DSTEP(ctrl)                                                            \
    { int t_ = __builtin_amdgcn_update_dpp(__float_as_int(x), __float_as_int(x),\
                                           (ctrl), 0xF, 0xF, false);           \
      x = fmaxf(x, __int_as_float(t_)); }
    DSTEP(0x111) DSTEP(0x112) DSTEP(0x114) DSTEP(0x118) DSTEP(0x142) DSTEP(0x143)
#undef DSTEP
    return __int_as_float(__builtin_amdgcn_readlane(__float_as_int(x), 63));
}

// One block (128 thr = 2 waves) per batch item.
// Wave 1 (producer): depth-2 pipelined gather of RAW probabilities
//   (p+eps; no logs) into a 2-slot LDS ring. Lanes l >= label_length skip
//   their label gathers (those states cannot reach the readout states).
// Wave 0 (consumer): scaled-CTC in probability domain. Per step:
//   am1 = s1[l-1] (DPP), n0=(s0+am1)*bb, n1=(s1+s0+skip*am1)*e, n2=(s2+s1)*bb.
//   Every 4 steps: renormalize all states by 2^-e (e from wave-max exponent),
//   accumulate e in eacc (exact integer bookkeeping). Final:
//   loss = -(log(v1+v2) + eacc*ln2).
extern "C" __global__ __launch_bounds__(128) void ctc_fwd(
    const float* __restrict__ y_pred,
    const int* __restrict__ labels,
    const int* __restrict__ input_length,
    const int* __restrict__ label_length,
    float* __restrict__ out)
{
    const int b   = blockIdx.x;
    const int l   = threadIdx.x & 63;
    const int wid = threadIdx.x >> 6;

    __shared__ float lab_lds[NSLOT][CH][LLAB];
    __shared__ float blank_lds[NSLOT][CH];

    int len = input_length[b];
    len = len < 1 ? 1 : (len > TT ? TT : len);
    const int tmax = len - 1;
    const int nch  = (len - 1 + CH - 1) / CH;

    int llm = label_length[b];
    llm = llm < 1 ? 1 : (llm > LLAB ? LLAB : llm);

    const int  lab   = labels[b * LLAB + l];
    const bool ldlab = (l < llm);   // label emits needed only for lanes < ll

    const float* __restrict__ yp = y_pred + (size_t)b * (TT * CC);
    const float* __restrict__ pl = yp + lab;       // this lane's label column
    const float* __restrict__ pb = yp + (CC - 1);  // blank column

    // consumer state
    float s0 = 0.f, s1 = 0.f, s2 = 0.f, skipf = 0.f;
    int   eacc = 0;

    // producer register sets
    float labA[CH], labB[CH], blA = 0.f, blB = 0.f;

#define ISSUE(c, labv, blv)                                                  \
    if ((c) < nch) {                                                         \
        const int t0 = 1 + (c) * CH;                                         \
        _Pragma("unroll")                                                    \
        for (int j = 0; j < CH; ++j) {                                       \
            int t = t0 + j; t = t > tmax ? tmax : t;                         \
            labv[j] = ldlab ? pl[t * CC] : 0.f;                              \
        }                                                                    \
        { int t = t0 + (l & (CH - 1)); t = t > tmax ? tmax : t;              \
          blv = pb[t * CC]; }                                                \
    }

#define FINISH(c, labv, blv)                                                 \
    if ((c) < nch) {                                                         \
        const int slot_ = (c) & (NSLOT - 1);                                 \
        if (l < CH) blank_lds[slot_][l] = blv + EPSF;                        \
        _Pragma("unroll")                                                    \
        for (int j = 0; j < CH; ++j)                                         \
            lab_lds[slot_][j][l] = ldlab ? (labv[j] + EPSF) : 0.f;           \
    }

    if (wid == 1) {
        ISSUE(0, labA, blA);
        ISSUE(1, labB, blB);
        FINISH(0, labA, blA);
    } else {
        const int labp = __shfl_up(lab, 1);
        skipf = (l >= 1 && lab != labp) ? 1.f : 0.f;
        if (l == 0) {               // alpha0: states 0 and 1
            s0 = pb[0] + EPSF;
            s1 = pl[0] + EPSF;
        }
    }
    __syncthreads();

    for (int k = 0; k < nch; ++k) {
        if (wid == 1) {
            // issue chunk k+2 (consumed next iter), finish chunk k+1
            // (its loads are one full iteration old -> counted vmcnt(33)).
            if ((k & 1) == 0) { ISSUE(k + 2, labA, blA); FINISH(k + 1, labB, blB); }
            else              { ISSUE(k + 2, labB, blB); FINISH(k + 1, labA, blA); }
        } else {
            const int slot = k & (NSLOT - 1);
            float e[CH], bb[CH];
#pragma unroll
            for (int j = 0; j < CH; ++j) {
                e[j]  = lab_lds[slot][j][l];
                bb[j] = blank_lds[slot][j];
            }
#pragma unroll
            for (int j = 0; j < CH; ++j) {
                const int t = 1 + k * CH + j;
                float am1 = wave_shr1_zero(s1);
                float n0 = (s0 + am1) * bb[j];                    // state 2l
                float n1 = fmaf(am1, skipf, s1 + s0) * e[j];      // state 2l+1
                float n2 = (s2 + s1) * bb[j];                     // state 128
                const bool act = t < len;
                s0 = act ? n0 : s0;
                s1 = act ? n1 : s1;
                s2 = act ? n2 : s2;
                if ((j & 3) == 3) {   // renormalize every 4 steps
                    float m = wave_max64(fmaxf(fmaxf(s0, s1), s2));
                    int me = __float_as_int(m) >> 23;             // biased exp
                    me = me < 26 ? 26 : me;                       // m==0 guard
                    float scale = __int_as_float((253 - me) << 23); // 2^(126-me)
                    s0 *= scale; s1 *= scale; s2 *= scale;
                    eacc += me - 126;                             // exact log2
                }
            }
        }
        __syncthreads();
    }

    if (wid == 0) {
        float v1 = __shfl(s1, llm - 1);                               // state 2ll-1
        float v2 = (llm < LLAB) ? __shfl(s0, llm) : __shfl(s2, 63);   // state 2ll
        float v  = fmaxf(v1 + v2, 1e-37f);
        if (l == 0) out[b] = -(__logf(v) + (float)eacc * LN2F);
    }
}

extern "C" void kernel_launch(void* const* d_in, const int* in_sizes, int n_in,
                              void* d_out, int out_size, void* d_ws, size_t ws_size,
                              hipStream_t stream) {
    (void)n_in; (void)out_size; (void)d_ws; (void)ws_size;
    const float* y_pred       = (const float*)d_in[0];
    const int*   labels       = (const int*)d_in[1];
    const int*   input_length = (const int*)d_in[2];
    const int*   label_length = (const int*)d_in[3];
    float* out = (float*)d_out;

    const int B = in_sizes[2];
    ctc_fwd<<<dim3(B), dim3(128), 0, stream>>>(y_pred, labels, input_length, label_length, out);
}